// Round 1
// baseline (499.858 us; speedup 1.0000x reference)
//
#include <hip/hip_runtime.h>
#include <hip/hip_bf16.h>

// 2-layer GCN (PyG GCNConv semantics) on MI355X.
// Pipeline (all on `stream`):
//   1. cnt[d]++ over dst  -> in-degree histogram
//   2. dinv[i] = rsqrt(cnt[i]+1)            (self-loop included)
//   3. 2-level exclusive scan(cnt) -> rowptr (CSR by dst)
//   4. fill colidx via rowptr + atomic slot counters (cnt reused, re-zeroed)
//   5. g1 = (x @ W1) * dinv[row]            (tiled LDS fp32 GEMM, 64-row tile)
//   6. t1[d] = relu(dinv[d]*(g1[d] + sum_{s->d} g1[s]) + b1)   (1 wave / node)
//   7. g2 = (t1 @ W2) * dinv[row]
//   8. out[d] = dinv[d]*(g2[d] + sum_{s->d} g2[s]) + b2        (32 lanes / node)
// Self-loops are folded into the accumulator init (acc = g[d]).

#define IN_DIM 128
#define HID_DIM 64
#define OUT_DIM 32

// ---------------------------------------------------------------- histogram
__global__ void k_count(const int* __restrict__ dst, int E, int* __restrict__ cnt) {
    int e = blockIdx.x * 256 + threadIdx.x;
    if (e < E) atomicAdd(&cnt[dst[e]], 1);
}

__global__ void k_dinv(const int* __restrict__ cnt, float* __restrict__ dinv, int N) {
    int i = blockIdx.x * 256 + threadIdx.x;
    if (i < N) dinv[i] = rsqrtf((float)cnt[i] + 1.0f);
}

// ---------------------------------------------------------------- scan (2-level)
// chunk = 1024 elements per block (256 threads x 4)
__global__ void k_chunk_sums(const int* __restrict__ cnt, int N, int* __restrict__ sums) {
    __shared__ int sdata[256];
    int t = threadIdx.x;
    int base = blockIdx.x * 1024 + t * 4;
    int s = 0;
#pragma unroll
    for (int i = 0; i < 4; ++i) {
        int idx = base + i;
        if (idx < N) s += cnt[idx];
    }
    sdata[t] = s;
    __syncthreads();
    for (int off = 128; off > 0; off >>= 1) {
        if (t < off) sdata[t] += sdata[t + off];
        __syncthreads();
    }
    if (t == 0) sums[blockIdx.x] = sdata[0];
}

// single block, exclusive scan of up to 1024 chunk sums (Hillis-Steele)
__global__ void k_scan_sums(int* __restrict__ sums, int nchunks) {
    __shared__ int buf[1024];
    int t = threadIdx.x;  // blockDim.x == 1024
    int v = (t < nchunks) ? sums[t] : 0;
    buf[t] = v;
    __syncthreads();
    for (int off = 1; off < 1024; off <<= 1) {
        int x = (t >= off) ? buf[t - off] : 0;
        __syncthreads();
        buf[t] += x;
        __syncthreads();
    }
    if (t < nchunks) sums[t] = buf[t] - v;  // exclusive
}

__global__ void k_scan_chunks(const int* __restrict__ cnt, int N,
                              const int* __restrict__ sums, int* __restrict__ rowptr, int E) {
    __shared__ int tsum[256];
    int t = threadIdx.x;
    int idx0 = blockIdx.x * 1024 + t * 4;
    int v[4];
    int s = 0;
#pragma unroll
    for (int i = 0; i < 4; ++i) {
        int idx = idx0 + i;
        v[i] = (idx < N) ? cnt[idx] : 0;
        s += v[i];
    }
    tsum[t] = s;
    __syncthreads();
    int mine = s;
    for (int off = 1; off < 256; off <<= 1) {
        int x = (t >= off) ? tsum[t - off] : 0;
        __syncthreads();
        tsum[t] += x;
        __syncthreads();
    }
    int run = tsum[t] - mine + sums[blockIdx.x];
#pragma unroll
    for (int i = 0; i < 4; ++i) {
        int idx = idx0 + i;
        if (idx < N) rowptr[idx] = run;
        run += v[i];
    }
    if (blockIdx.x == 0 && t == 0) rowptr[N] = E;
}

// ---------------------------------------------------------------- CSR fill
__global__ void k_fill(const int* __restrict__ src, const int* __restrict__ dst, int E,
                       const int* __restrict__ rowptr, int* __restrict__ fill,
                       int* __restrict__ colidx) {
    int e = blockIdx.x * 256 + threadIdx.x;
    if (e < E) {
        int d = dst[e];
        int pos = rowptr[d] + atomicAdd(&fill[d], 1);
        colidx[pos] = src[e];
    }
}

// ---------------------------------------------------------------- GEMM1: g1 = (x @ W1) * dinv
// 64-row M-tile, full K=128, full N=64. 256 threads, 4x4 micro-tile.
// LDS: xs 64x128 fp32 (32KB) + ws 128x64 fp32 (32KB) = 64KB exactly.
__global__ __launch_bounds__(256) void k_gemm1(const float* __restrict__ x,
                                               const float* __restrict__ W,
                                               const float* __restrict__ dinv,
                                               float* __restrict__ g1, int N) {
    __shared__ float xs[64 * 128];
    __shared__ float ws[128 * 64];
    int t = threadIdx.x;
    int row0 = blockIdx.x * 64;

    // stage W1 (2048 float4)
    const float4* W4 = (const float4*)W;
    float4* ws4 = (float4*)ws;
#pragma unroll
    for (int i = 0; i < 8; ++i) ws4[t + 256 * i] = W4[t + 256 * i];
    // stage x tile (2048 float4)
#pragma unroll
    for (int i = 0; i < 8; ++i) {
        int l = t + 256 * i;
        int r = l >> 5;    // 32 float4 per row
        int c4 = l & 31;
        int row = row0 + r;
        float4 val = make_float4(0.f, 0.f, 0.f, 0.f);
        if (row < N) val = ((const float4*)(x + (size_t)row * IN_DIM))[c4];
        *(float4*)&xs[r * IN_DIM + c4 * 4] = val;
    }
    __syncthreads();

    int tx = t & 15;   // 16 col groups x 4 cols
    int ty = t >> 4;   // 16 row groups x 4 rows
    float acc[4][4] = {};
    for (int k = 0; k < 128; k += 4) {
        float a[4][4], b[4][4];
#pragma unroll
        for (int i = 0; i < 4; ++i)
            *(float4*)a[i] = *(const float4*)&xs[(ty * 4 + i) * IN_DIM + k];
#pragma unroll
        for (int kk = 0; kk < 4; ++kk)
            *(float4*)b[kk] = *(const float4*)&ws[(k + kk) * HID_DIM + tx * 4];
#pragma unroll
        for (int i = 0; i < 4; ++i)
#pragma unroll
            for (int kk = 0; kk < 4; ++kk)
#pragma unroll
                for (int j = 0; j < 4; ++j)
                    acc[i][j] += a[i][kk] * b[kk][j];
    }
#pragma unroll
    for (int i = 0; i < 4; ++i) {
        int row = row0 + ty * 4 + i;
        if (row < N) {
            float dv = dinv[row];
            float4 r;
            r.x = acc[i][0] * dv; r.y = acc[i][1] * dv;
            r.z = acc[i][2] * dv; r.w = acc[i][3] * dv;
            ((float4*)(g1 + (size_t)row * HID_DIM))[tx] = r;
        }
    }
}

// ---------------------------------------------------------------- GEMM2: g2 = (t1 @ W2) * dinv
// 64-row tile, K=64, N=32. 256 threads, 2x4 micro-tile. xs padded +4 floats.
__global__ __launch_bounds__(256) void k_gemm2(const float* __restrict__ t1,
                                               const float* __restrict__ W,
                                               const float* __restrict__ dinv,
                                               float* __restrict__ g2, int N) {
    __shared__ float xs[64 * 68];
    __shared__ float ws[64 * 32];
    int t = threadIdx.x;
    int row0 = blockIdx.x * 64;

    const float4* W4 = (const float4*)W;  // 512 float4
    float4* ws4 = (float4*)ws;
#pragma unroll
    for (int i = 0; i < 2; ++i) ws4[t + 256 * i] = W4[t + 256 * i];
#pragma unroll
    for (int i = 0; i < 4; ++i) {
        int l = t + 256 * i;   // 0..1023
        int r = l >> 4;        // 16 float4 per row
        int c4 = l & 15;
        int row = row0 + r;
        float4 val = make_float4(0.f, 0.f, 0.f, 0.f);
        if (row < N) val = ((const float4*)(t1 + (size_t)row * HID_DIM))[c4];
        *(float4*)&xs[r * 68 + c4 * 4] = val;
    }
    __syncthreads();

    int tx = t & 7;    // 8 col groups x 4 cols
    int ty = t >> 3;   // 32 row groups x 2 rows
    float acc[2][4] = {};
    for (int k = 0; k < 64; k += 4) {
        float a[2][4], b[4][4];
#pragma unroll
        for (int i = 0; i < 2; ++i)
            *(float4*)a[i] = *(const float4*)&xs[(ty * 2 + i) * 68 + k];
#pragma unroll
        for (int kk = 0; kk < 4; ++kk)
            *(float4*)b[kk] = *(const float4*)&ws[(k + kk) * OUT_DIM + tx * 4];
#pragma unroll
        for (int i = 0; i < 2; ++i)
#pragma unroll
            for (int kk = 0; kk < 4; ++kk)
#pragma unroll
                for (int j = 0; j < 4; ++j)
                    acc[i][j] += a[i][kk] * b[kk][j];
    }
#pragma unroll
    for (int i = 0; i < 2; ++i) {
        int row = row0 + ty * 2 + i;
        if (row < N) {
            float dv = dinv[row];
            float4 r;
            r.x = acc[i][0] * dv; r.y = acc[i][1] * dv;
            r.z = acc[i][2] * dv; r.w = acc[i][3] * dv;
            ((float4*)(g2 + (size_t)row * OUT_DIM))[tx] = r;
        }
    }
}

// ---------------------------------------------------------------- aggregation
// Layer 1: one 64-lane wave per dst node; lane = feature column.
// t1[d] = relu(dinv[d]*(g1[d] + sum g1[s]) + b1)
__global__ __launch_bounds__(256) void k_agg1(const float* __restrict__ g1,
                                              const int* __restrict__ rowptr,
                                              const int* __restrict__ colidx,
                                              const float* __restrict__ dinv,
                                              const float* __restrict__ b1,
                                              float* __restrict__ t1, int N) {
    int d = (blockIdx.x * 256 + threadIdx.x) >> 6;
    int lane = threadIdx.x & 63;
    if (d >= N) return;
    float acc = g1[(size_t)d * HID_DIM + lane];  // self-loop
    int beg = rowptr[d], end = rowptr[d + 1];
    if (beg < end) {
        int s_next = colidx[beg];
        for (int e = beg; e < end; ++e) {
            int s = s_next;
            if (e + 1 < end) s_next = colidx[e + 1];
            acc += g1[(size_t)s * HID_DIM + lane];
        }
    }
    float v = dinv[d] * acc + b1[lane];
    t1[(size_t)d * HID_DIM + lane] = v > 0.f ? v : 0.f;
}

// Layer 2: one 32-lane group per dst node; writes final output.
__global__ __launch_bounds__(256) void k_agg2(const float* __restrict__ g2,
                                              const int* __restrict__ rowptr,
                                              const int* __restrict__ colidx,
                                              const float* __restrict__ dinv,
                                              const float* __restrict__ b2,
                                              float* __restrict__ out, int N) {
    int d = (blockIdx.x * 256 + threadIdx.x) >> 5;
    int lane = threadIdx.x & 31;
    if (d >= N) return;
    float acc = g2[(size_t)d * OUT_DIM + lane];  // self-loop
    int beg = rowptr[d], end = rowptr[d + 1];
    if (beg < end) {
        int s_next = colidx[beg];
        for (int e = beg; e < end; ++e) {
            int s = s_next;
            if (e + 1 < end) s_next = colidx[e + 1];
            acc += g2[(size_t)s * OUT_DIM + lane];
        }
    }
    out[(size_t)d * OUT_DIM + lane] = dinv[d] * acc + b2[lane];
}

// ---------------------------------------------------------------- launch
extern "C" void kernel_launch(void* const* d_in, const int* in_sizes, int n_in,
                              void* d_out, int out_size, void* d_ws, size_t ws_size,
                              hipStream_t stream) {
    const float* x  = (const float*)d_in[0];
    const int*   ei = (const int*)d_in[1];
    const float* W1 = (const float*)d_in[2];
    const float* b1 = (const float*)d_in[3];
    const float* W2 = (const float*)d_in[4];
    const float* b2 = (const float*)d_in[5];
    float* out = (float*)d_out;

    const int N = in_sizes[0] / IN_DIM;
    const int E = in_sizes[1] / 2;
    const int* src = ei;
    const int* dst = ei + E;

    // workspace carve (256B aligned). Total ~72 MB.
    char* p = (char*)d_ws;
    auto alloc = [&](size_t bytes) -> void* {
        void* r = (void*)p;
        p += (bytes + 255) & ~(size_t)255;
        return r;
    };
    int nchunks = (N + 1023) / 1024;
    int*   cnt    = (int*)alloc((size_t)N * 4);        // histogram, reused as fill ctr
    int*   rowptr = (int*)alloc((size_t)(N + 1) * 4);
    int*   sums   = (int*)alloc((size_t)nchunks * 4);
    float* dinv   = (float*)alloc((size_t)N * 4);
    int*   colidx = (int*)alloc((size_t)E * 4);
    float* g1     = (float*)alloc((size_t)N * HID_DIM * 4);
    float* t1     = (float*)alloc((size_t)N * HID_DIM * 4);
    float* g2     = (float*)alloc((size_t)N * OUT_DIM * 4);

    hipMemsetAsync(cnt, 0, (size_t)N * 4, stream);
    k_count<<<(E + 255) / 256, 256, 0, stream>>>(dst, E, cnt);
    k_dinv<<<(N + 255) / 256, 256, 0, stream>>>(cnt, dinv, N);
    k_chunk_sums<<<nchunks, 256, 0, stream>>>(cnt, N, sums);
    k_scan_sums<<<1, 1024, 0, stream>>>(sums, nchunks);
    k_scan_chunks<<<nchunks, 256, 0, stream>>>(cnt, N, sums, rowptr, E);
    hipMemsetAsync(cnt, 0, (size_t)N * 4, stream);
    k_fill<<<(E + 255) / 256, 256, 0, stream>>>(src, dst, E, rowptr, cnt, colidx);

    k_gemm1<<<(N + 63) / 64, 256, 0, stream>>>(x, W1, dinv, g1, N);
    k_agg1<<<(N + 3) / 4, 256, 0, stream>>>(g1, rowptr, colidx, dinv, b1, t1, N);
    k_gemm2<<<(N + 63) / 64, 256, 0, stream>>>(t1, W2, dinv, g2, N);
    k_agg2<<<(N + 7) / 8, 256, 0, stream>>>(g2, rowptr, colidx, dinv, b2, out, N);
}